// Round 9
// baseline (402.425 us; speedup 1.0000x reference)
//
#include <hip/hip_runtime.h>
#include <stdint.h>

#pragma clang fp contract(off)

#define N_PRIORS   400000
#define NCLS       81
#define TILE       128
#define RED_BLOCKS (N_PRIORS / TILE)   // 3125
#define HGRID      512
#define CAND_CAP   8192
#define TOPK       1000
#define CM_CAP     448                 // rows cached in LDS for serial NMS

// ---- workspace layout (bytes). First OFF_CAND bytes zeroed each launch. ----
// ctrl u32[32]: [0]=thrc (exclusive upper bound on bits(1-s)) [2]=cand_cnt
//   [3]=master done [6]=iou done [7]=CM slot counter [8..15]=sub done counters
#define OFF_CTRL    0
#define OFF_RNZ     3200     // u64[16] row-has-suppression bits
#define OFF_VALID   3328     // u64[16] valid bits (score > 0.3)
#define OFF_SLOT    4096     // u32[1000] row -> CM slot+1 (0 = none)
#define OFF_CSCORE  8192     // f32[1024]
#define OFF_CLABEL  12288    // s32[1024]
#define OFF_CRAW    16384    // f32[1024][4] raw boxes
#define OFF_OBOX    32768    // f32[1024][4] offset boxes (zeroed tail)
#define OFF_OAREA   49152    // f32[1024]
#define OFF_HIST16  65536    // u32[65536] hist over bits(1-s)>>16 (256 KB)
#define OFF_CAND    327680   // u64[8192]
#define OFF_CM      393216   // u64[1000][16] compacted suppression rows
#define OFF_KEYS    524288   // u64[400000]
#define OFF_LABELS  (OFF_KEYS + N_PRIORS * 8)  // s32[400000]

__device__ __forceinline__ uint32_t atomLoadU32(const uint32_t* p) {
  return __hip_atomic_load(p, __ATOMIC_RELAXED, __HIP_MEMORY_SCOPE_AGENT);
}
__device__ __forceinline__ uint64_t atomLoadU64(const uint64_t* p) {
  return __hip_atomic_load(p, __ATOMIC_RELAXED, __HIP_MEMORY_SCOPE_AGENT);
}
__device__ __forceinline__ void atomStoreU64(uint64_t* p, uint64_t v) {
  __hip_atomic_store(p, v, __ATOMIC_RELAXED, __HIP_MEMORY_SCOPE_AGENT);
}
__device__ __forceinline__ void atomStoreU32(uint32_t* p, uint32_t v) {
  __hip_atomic_store(p, v, __ATOMIC_RELAXED, __HIP_MEMORY_SCOPE_AGENT);
}

// async HBM->LDS DMA, 16B per lane; LDS dest = wave-uniform base + lane*16
__device__ __forceinline__ void gload_lds16(const void* g, void* l) {
  __builtin_amdgcn_global_load_lds(
      (const __attribute__((address_space(1))) void*)g,
      (__attribute__((address_space(3))) void*)l, 16, 0, 0);
}

// monotone rebinning: larger score s -> smaller bits(1-s). Exact for s in
// [0.5,1] (Sterbenz); monotone non-increasing for all s. Bin = top 16 bits.
__device__ __forceinline__ uint32_t cbits(float s) {
  float c = 1.0f - s;
  return __float_as_uint(c);
}

// ---- Phase 1: max/argmax over classes 1..80 + key pack + hist(1-s) +
//      (last block) ascending threshold select over 65536 bins ----
__global__ __launch_bounds__(256) void k_reduce(const float* __restrict__ scores,
                                                uint8_t* __restrict__ ws) {
  __shared__ __align__(16) float s_tile[TILE * NCLS];  // 41472 B
  __shared__ uint32_t s_hist[256];
  __shared__ uint32_t s_wt[4];
  __shared__ uint32_t s_win, s_excl;
  __shared__ int s_last;
  uint32_t* ctrl   = (uint32_t*)(ws + OFF_CTRL);
  uint32_t* hist16 = (uint32_t*)(ws + OFF_HIST16);
  uint64_t* keys   = (uint64_t*)(ws + OFF_KEYS);
  int32_t*  labs   = (int32_t*)(ws + OFF_LABELS);
  const int tid = threadIdx.x;

  // HBM->LDS DMA staging of the 128-prior tile: 40 x 1KB chunks round-robin
  const float* src = scores + (size_t)blockIdx.x * (TILE * NCLS);
  {
    const int wave = tid >> 6, lane = tid & 63;
    const char* gbase = (const char*)src + lane * 16;
    char* lbase = (char*)s_tile;
    #pragma unroll
    for (int c = wave; c < 40; c += 4)
      gload_lds16(gbase + c * 1024, lbase + c * 1024);
  }
  // tail 512B: half-wave reg-staged
  if (tid < 32) {
    float4 v = ((const float4*)src)[2560 + tid];
    ((float4*)s_tile)[2560 + tid] = v;
  }
  __syncthreads();   // drains vmcnt (DMA) + lgkmcnt (tail ds_write)

  // 2 threads per prior: half 0 -> classes 1..40, half 1 -> 41..80
  const int pl = tid >> 1, half = tid & 1;
  const float* row = s_tile + pl * NCLS + 1 + half * 40;
  float best = -1.0f; int lab = 0;
  #pragma unroll
  for (int c = 0; c < 40; ++c) {           // strict > keeps first occurrence
    float v = row[c];
    if (v > best) { best = v; lab = c; }
  }
  lab += half * 40;
  float obst = __shfl_xor(best, 1);
  int   olab = __shfl_xor(lab, 1);
  float b0 = half ? obst : best;  int l0 = half ? olab : lab;
  float b1 = half ? best : obst;  int l1 = half ? lab  : olab;
  float fb = (b1 > b0) ? b1 : b0;          // tie -> lower label = first occurrence
  int   fl = (b1 > b0) ? l1 : l0;

  if (half == 0) {
    int p = blockIdx.x * TILE + pl;
    uint32_t bits = __float_as_uint(fb);   // scores >= 0: bit order == float order
    keys[p] = ((uint64_t)bits << 32) | (uint32_t)(~(uint32_t)p);
    labs[p] = fl;
    atomicAdd(&hist16[cbits(fb) >> 16], 1u);  // bin by bits(1-s): fine near s=1
  }
  __syncthreads();                         // drains vmcnt before done-count
  if (tid == 0) {
    // two-level done counter: 8 sub-counters cut same-address RMW contention 8x
    int r = blockIdx.x & 7;
    uint32_t target = (RED_BLOCKS >> 3) + ((uint32_t)r < (RED_BLOCKS & 7) ? 1u : 0u);
    int last = 0;
    if (atomicAdd(&ctrl[8 + r], 1u) == target - 1u)
      last = (atomicAdd(&ctrl[3], 1u) == 7u);
    s_last = last;
  }
  __syncthreads();
  if (!s_last) return;

  // ---- last block: ascending select. bin 0 = best scores. Find bin B with
  //      cum(0..B-1) < TOPK <= cum(0..B); candidates = bins <= B. ----
  {
    const int lane = tid & 63, wid = tid >> 6;
    const int cbase = 256 * tid;           // ascending chunk of 256 bins
    uint32_t csum = 0;
    for (int b = 0; b < 256; ++b) csum += atomLoadU32(&hist16[cbase + b]);
    uint32_t incl = csum;
    #pragma unroll
    for (int d = 1; d < 64; d <<= 1) {
      uint32_t up = __shfl_up(incl, d);
      if (lane >= d) incl += up;
    }
    if (lane == 63) s_wt[wid] = incl;
    __syncthreads();
    uint32_t woff = 0;
    #pragma unroll
    for (int w = 0; w < 4; ++w) if (w < wid) woff += s_wt[w];
    incl += woff;
    uint32_t excl = incl - csum;
    if (excl < TOPK && TOPK <= incl) { s_win = tid; s_excl = excl; }  // unique
    __syncthreads();
    const int winbase = 256 * s_win;
    s_hist[tid] = atomLoadU32(&hist16[winbase + tid]);
    __syncthreads();
    if (tid < 64) {
      const uint32_t k2 = TOPK - s_excl;   // in [1, chunk_sum]
      uint32_t h[4];
      #pragma unroll
      for (int t = 0; t < 4; ++t) h[t] = s_hist[4 * tid + t];   // ascending
      uint32_t part = h[0] + h[1] + h[2] + h[3];
      uint32_t incl2 = part;
      #pragma unroll
      for (int d = 1; d < 64; d <<= 1) {
        uint32_t up = __shfl_up(incl2, d);
        if (tid >= d) incl2 += up;
      }
      uint32_t excl2 = incl2 - part;
      if (excl2 < k2 && k2 <= incl2) {
        uint32_t cum = excl2;
        #pragma unroll
        for (int t = 0; t < 4; ++t) {
          if (cum + h[t] >= k2) {
            uint32_t B = (uint32_t)winbase + 4 * tid + t;
            atomStoreU32(&ctrl[0], (B + 1u) << 16);   // excl. bound on bits(1-s)
            break;
          }
          cum += h[t];
        }
      }
    }
  }
}

// ---- Phase 2: compact candidate superset (bits(1-s) < thrc) ----
__global__ __launch_bounds__(256) void k_compact(uint8_t* __restrict__ ws) {
  uint32_t* ctrl = (uint32_t*)(ws + OFF_CTRL);
  const uint64_t* keys = (const uint64_t*)(ws + OFF_KEYS);
  uint64_t* cand = (uint64_t*)(ws + OFF_CAND);
  const uint32_t thrc = ctrl[0];
  const int tid = threadIdx.x;
  for (int i = blockIdx.x * 256 + tid; i < N_PRIORS; i += 256 * HGRID) {
    uint64_t kk = keys[i];
    float s = __uint_as_float((uint32_t)(kk >> 32));
    if (cbits(s) < thrc) {                 // same transform as k_reduce: exact
      uint32_t pos = atomicAdd(&ctrl[2], 1u);
      if (pos < CAND_CAP) cand[pos] = kk;
    }
  }
}

// ---- Phase 3: exact rank (pairwise) + scatter top-1000 in top_k order ----
__global__ __launch_bounds__(256) void k_rank(const float* __restrict__ boxes,
                                              uint8_t* __restrict__ ws) {
  uint32_t* ctrl = (uint32_t*)(ws + OFF_CTRL);
  const uint64_t* cand = (const uint64_t*)(ws + OFF_CAND);
  const int32_t* labs = (const int32_t*)(ws + OFF_LABELS);
  float*   cscore = (float*)(ws + OFF_CSCORE);
  int32_t* clabel = (int32_t*)(ws + OFF_CLABEL);
  float*   craw   = (float*)(ws + OFF_CRAW);
  float*   obox   = (float*)(ws + OFF_OBOX);
  float*   oarea  = (float*)(ws + OFF_OAREA);
  uint64_t* validm = (uint64_t*)(ws + OFF_VALID);
  uint32_t c2 = ctrl[2];
  const uint32_t n = (c2 < CAND_CAP) ? c2 : CAND_CAP;
  const uint32_t j = blockIdx.x;
  if (j >= n) return;
  const uint64_t kj = cand[j];
  const int tid = threadIdx.x;
  uint32_t cnt = 0;
  for (uint32_t i = tid; i < n; i += 256) cnt += (cand[i] > kj) ? 1u : 0u;
  __shared__ uint32_t red[256];
  red[tid] = cnt;
  __syncthreads();
  #pragma unroll
  for (int s = 128; s > 0; s >>= 1) {
    if (tid < s) red[tid] += red[tid + s];
    __syncthreads();
  }
  if (tid == 0) {
    uint32_t rank = red[0];   // keys unique -> ranks unique & complete for top-1000
    if (rank < TOPK) {
      uint32_t idx = ~(uint32_t)kj;
      float sc = __uint_as_float((uint32_t)(kj >> 32));
      int lab = labs[idx];
      float bx0 = boxes[idx * 4 + 0];
      float bx1 = boxes[idx * 4 + 1];
      float bx2 = boxes[idx * 4 + 2];
      float bx3 = boxes[idx * 4 + 3];
      float off = (float)lab * 4.0f;
      float o0 = bx0 + off, o1 = bx1 + off, o2 = bx2 + off, o3 = bx3 + off;
      cscore[rank] = sc;
      clabel[rank] = lab;
      craw[rank * 4 + 0] = bx0; craw[rank * 4 + 1] = bx1;
      craw[rank * 4 + 2] = bx2; craw[rank * 4 + 3] = bx3;
      obox[rank * 4 + 0] = o0;  obox[rank * 4 + 1] = o1;
      obox[rank * 4 + 2] = o2;  obox[rank * 4 + 3] = o3;
      oarea[rank] = (o2 - o0) * (o3 - o1);
      if (sc > 0.3f)
        atomicOr((unsigned long long*)&validm[rank >> 6], 1ull << (rank & 63));
    }
  }
}

// ---- Phase 4: IoU rows (compacted) + (last block) LDS-cached serial NMS + output ----
__global__ __launch_bounds__(256) void k_iou_nms(float* __restrict__ out,
                                                 uint8_t* __restrict__ ws) {
  __shared__ uint64_t s_words[16];
  __shared__ uint32_t s_slotsh;
  __shared__ int s_last;
  __shared__ uint64_t s_keep[16];
  __shared__ uint16_t s_slot[TOPK];          // 2000 B
  __shared__ uint64_t s_cm[CM_CAP * 16];     // 57344 B

  uint32_t* ctrl = (uint32_t*)(ws + OFF_CTRL);
  const float* obox  = (const float*)(ws + OFF_OBOX);
  const float* oarea = (const float*)(ws + OFF_OAREA);
  uint64_t* CM  = (uint64_t*)(ws + OFF_CM);
  uint64_t* rnz = (uint64_t*)(ws + OFF_RNZ);
  uint32_t* slotmap = (uint32_t*)(ws + OFF_SLOT);
  const uint64_t* validm = (const uint64_t*)(ws + OFF_VALID);
  const float*   cscore = (const float*)(ws + OFF_CSCORE);
  const int32_t* clabel = (const int32_t*)(ws + OFF_CLABEL);
  const float*   craw   = (const float*)(ws + OFF_CRAW);

  const int i = blockIdx.x;
  const int tid = threadIdx.x;
  const float bi0 = obox[i * 4 + 0], bi1 = obox[i * 4 + 1];
  const float bi2 = obox[i * 4 + 2], bi3 = obox[i * 4 + 3];
  const float ai = oarea[i];
  #pragma unroll
  for (int k = 0; k < 4; ++k) {
    int j = tid + 256 * k;                      // [0,1024); tail zeroed
    const float4 bj = ((const float4*)obox)[j];
    float x1 = fmaxf(bi0, bj.x);
    float y1 = fmaxf(bi1, bj.y);
    float x2 = fminf(bi2, bj.z);
    float y2 = fminf(bi3, bj.w);
    float iw = fmaxf(x2 - x1, 0.0f);
    float ih = fmaxf(y2 - y1, 0.0f);
    float inter = iw * ih;
    float uni = ai + oarea[j] - inter;
    float iou = inter / fmaxf(uni, 1e-9f);
    bool pred = (iou > 0.5f) && (j > i) && (j < TOPK);
    uint64_t m = __ballot(pred);
    if ((tid & 63) == 0) s_words[(tid >> 6) + 4 * k] = m;
  }
  __syncthreads();
  if (tid == 0) {
    uint64_t any = 0;
    #pragma unroll
    for (int w = 0; w < 16; ++w) any |= s_words[w];
    uint32_t sl = 0xFFFFFFFFu;
    if (any) {
      sl = atomicAdd(&ctrl[7], 1u);
      atomicOr((unsigned long long*)&rnz[i >> 6], 1ull << (i & 63));
      atomStoreU32(&slotmap[i], sl + 1u);
    }
    s_slotsh = sl;
  }
  __syncthreads();
  {
    uint32_t sl = s_slotsh;
    if (sl != 0xFFFFFFFFu && tid < 16)
      atomStoreU64(&CM[(size_t)sl * 16 + tid], s_words[tid]);
  }
  __syncthreads();                            // drain before done-count
  if (tid == 0) s_last = (atomicAdd(&ctrl[6], 1u) == (uint32_t)(TOPK - 1));
  __syncthreads();
  if (!s_last) return;

  // ---- last block: prefetch compacted rows to LDS, serial NMS, outputs ----
  uint32_t cmcnt = atomLoadU32(&ctrl[7]);     // <= 1000
  uint32_t ncm = cmcnt < CM_CAP ? cmcnt : CM_CAP;
  for (int r = tid; r < TOPK; r += 256)
    s_slot[r] = (uint16_t)atomLoadU32(&slotmap[r]);
  for (uint32_t x = tid; x < ncm * 16; x += 256)
    s_cm[x] = atomLoadU64(&CM[x]);
  __syncthreads();

  if (tid < 64) {
    const int lane = tid;
    uint64_t keep = 0, rz = 0;
    if (lane < 16) {
      keep = validm[lane];            // written by previous kernel (boundary-coherent)
      rz = atomLoadU64(&rnz[lane]);
    }
    for (int w = 0; w < 16; ++w) {
      uint64_t rw = __shfl(rz, w);
      int start = 0;
      while (true) {
        uint64_t kw = __shfl(keep, w);
        uint64_t act = kw & rw;
        if (start) act &= (~0ull) << start;
        if (!act) break;
        int il = __builtin_ctzll(act);
        int row = w * 64 + il;
        uint32_t sv = s_slot[row];
        uint64_t m = 0;
        if (lane < 16 && sv) {
          uint32_t s = sv - 1u;
          m = (s < ncm) ? s_cm[s * 16 + lane]
                        : atomLoadU64(&CM[(size_t)s * 16 + lane]);
        }
        keep &= ~m;
        if (il >= 63) break;
        start = il + 1;
      }
    }
    if (lane < 16) s_keep[lane] = keep;
  }
  __syncthreads();

  // outputs: boxes[4000] | labels[1000] | probs[1000] | keep[1000], all f32
  for (int e = tid; e < 4000; e += 256) {
    int j = e >> 2;
    bool kp = (s_keep[j >> 6] >> (j & 63)) & 1ull;
    out[e] = kp ? craw[e] : 0.0f;
  }
  for (int j = tid; j < TOPK; j += 256) {
    bool kp = (s_keep[j >> 6] >> (j & 63)) & 1ull;
    out[4000 + j] = kp ? (float)(clabel[j] + 1) : 0.0f;
    out[5000 + j] = kp ? cscore[j] : 0.0f;
    out[6000 + j] = kp ? 1.0f : 0.0f;
  }
}

extern "C" void kernel_launch(void* const* d_in, const int* in_sizes, int n_in,
                              void* d_out, int out_size, void* d_ws, size_t ws_size,
                              hipStream_t stream) {
  const float* scores = (const float*)d_in[0];
  const float* boxes  = (const float*)d_in[1];
  float* out = (float*)d_out;
  uint8_t* ws = (uint8_t*)d_ws;

  (void)in_sizes; (void)n_in; (void)out_size; (void)ws_size;

  hipMemsetAsync(d_ws, 0, OFF_CAND, stream);   // ctrl..hist16 zeroed (320 KB)
  k_reduce<<<RED_BLOCKS, 256, 0, stream>>>(scores, ws);
  k_compact<<<HGRID, 256, 0, stream>>>(ws);
  k_rank<<<CAND_CAP, 256, 0, stream>>>(boxes, ws);
  k_iou_nms<<<TOPK, 256, 0, stream>>>(out, ws);
}

// Round 10
// 269.234 us; speedup vs baseline: 1.4947x; 1.4947x over previous
//
#include <hip/hip_runtime.h>
#include <stdint.h>

#pragma clang fp contract(off)

#define N_PRIORS   400000
#define NCLS       81
#define TILE       128
#define RED_BLOCKS (N_PRIORS / TILE)   // 3125
#define HGRID      512
#define CAND_CAP   8192
#define TOPK       1000
#define CM_CAP     448                 // rows cached in LDS for serial NMS

// ---- workspace layout (bytes). First 65536 bytes zeroed each launch. ----
// ctrl u32[32]: [0]=thrc (exclusive bound on bits(1-s)) [2]=cand_cnt
//   [3]=master done [6]=iou done [7]=CM slot counter [8..15]=sub done counters
#define OFF_CTRL    0
#define OFF_HIST256 128      // u32[256] hist over bits(1-s)>>24
#define OFF_RNZ     3200     // u64[16] row-has-suppression bits
#define OFF_VALID   3328     // u64[16] valid bits (score > 0.3)
#define OFF_SLOT    4096     // u32[1000] row -> CM slot+1 (0 = none)
#define OFF_CSCORE  8192     // f32[1024]
#define OFF_CLABEL  12288    // s32[1024]
#define OFF_CRAW    16384    // f32[1024][4] raw boxes
#define OFF_OBOX    32768    // f32[1024][4] offset boxes (zeroed tail)
#define OFF_OAREA   49152    // f32[1024]
#define OFF_CAND    65536    // u64[8192]
#define OFF_CM      131072   // u64[1000][16] compacted suppression rows
#define OFF_KEYS    262144   // u64[400000]
#define OFF_LABELS  (OFF_KEYS + N_PRIORS * 8)  // s32[400000]

__device__ __forceinline__ uint32_t atomLoadU32(const uint32_t* p) {
  return __hip_atomic_load(p, __ATOMIC_RELAXED, __HIP_MEMORY_SCOPE_AGENT);
}
__device__ __forceinline__ uint64_t atomLoadU64(const uint64_t* p) {
  return __hip_atomic_load(p, __ATOMIC_RELAXED, __HIP_MEMORY_SCOPE_AGENT);
}
__device__ __forceinline__ void atomStoreU64(uint64_t* p, uint64_t v) {
  __hip_atomic_store(p, v, __ATOMIC_RELAXED, __HIP_MEMORY_SCOPE_AGENT);
}
__device__ __forceinline__ void atomStoreU32(uint32_t* p, uint32_t v) {
  __hip_atomic_store(p, v, __ATOMIC_RELAXED, __HIP_MEMORY_SCOPE_AGENT);
}

// async HBM->LDS DMA, 16B per lane; LDS dest = wave-uniform base + lane*16
__device__ __forceinline__ void gload_lds16(const void* g, void* l) {
  __builtin_amdgcn_global_load_lds(
      (const __attribute__((address_space(1))) void*)g,
      (__attribute__((address_space(3))) void*)l, 16, 0, 0);
}

// monotone rebinning: larger score s -> smaller bits(1-s). Exact for s in
// [0.5,1] (Sterbenz); monotone non-increasing for all s. Fine near s=1.
__device__ __forceinline__ uint32_t cbits(float s) {
  float c = 1.0f - s;
  return __float_as_uint(c);
}

// ---- Phase 1: max/argmax over classes 1..80 + key pack + LDS-aggregated
//      256-bin hist on cbits>>24 + (last block) ascending select ----
__global__ __launch_bounds__(256) void k_reduce(const float* __restrict__ scores,
                                                uint8_t* __restrict__ ws) {
  __shared__ __align__(16) float s_tile[TILE * NCLS];  // 41472 B
  __shared__ uint32_t s_hist[256];
  __shared__ int s_last;
  uint32_t* ctrl    = (uint32_t*)(ws + OFF_CTRL);
  uint32_t* hist256 = (uint32_t*)(ws + OFF_HIST256);
  uint64_t* keys    = (uint64_t*)(ws + OFF_KEYS);
  int32_t*  labs    = (int32_t*)(ws + OFF_LABELS);
  const int tid = threadIdx.x;
  s_hist[tid] = 0;

  // HBM->LDS DMA staging of the 128-prior tile: 40 x 1KB chunks round-robin
  const float* src = scores + (size_t)blockIdx.x * (TILE * NCLS);
  {
    const int wave = tid >> 6, lane = tid & 63;
    const char* gbase = (const char*)src + lane * 16;
    char* lbase = (char*)s_tile;
    #pragma unroll
    for (int c = wave; c < 40; c += 4)
      gload_lds16(gbase + c * 1024, lbase + c * 1024);
  }
  // tail 512B: half-wave reg-staged
  if (tid < 32) {
    float4 v = ((const float4*)src)[2560 + tid];
    ((float4*)s_tile)[2560 + tid] = v;
  }
  __syncthreads();   // drains vmcnt (DMA) + lgkmcnt (tail ds_write)

  // 2 threads per prior: half 0 -> classes 1..40, half 1 -> 41..80
  const int pl = tid >> 1, half = tid & 1;
  const float* row = s_tile + pl * NCLS + 1 + half * 40;
  float best = -1.0f; int lab = 0;
  #pragma unroll
  for (int c = 0; c < 40; ++c) {           // strict > keeps first occurrence
    float v = row[c];
    if (v > best) { best = v; lab = c; }
  }
  lab += half * 40;
  float obst = __shfl_xor(best, 1);
  int   olab = __shfl_xor(lab, 1);
  float b0 = half ? obst : best;  int l0 = half ? olab : lab;
  float b1 = half ? best : obst;  int l1 = half ? lab  : olab;
  float fb = (b1 > b0) ? b1 : b0;          // tie -> lower label = first occurrence
  int   fl = (b1 > b0) ? l1 : l0;

  if (half == 0) {
    int p = blockIdx.x * TILE + pl;
    uint32_t bits = __float_as_uint(fb);   // scores >= 0: bit order == float order
    keys[p] = ((uint64_t)bits << 32) | (uint32_t)(~(uint32_t)p);
    labs[p] = fl;
    atomicAdd(&s_hist[cbits(fb) >> 24], 1u);   // LDS-aggregated (256 bins)
  }
  __syncthreads();
  {
    uint32_t h = s_hist[tid];
    if (h) atomicAdd(&hist256[tid], h);    // 256 global addresses only: fast
  }
  __syncthreads();                         // drains vmcnt before done-count
  if (tid == 0) {
    // two-level done counter: 8 sub-counters cut same-address RMW contention 8x
    int r = blockIdx.x & 7;
    uint32_t target = (RED_BLOCKS >> 3) + ((uint32_t)r < (RED_BLOCKS & 7) ? 1u : 0u);
    int last = 0;
    if (atomicAdd(&ctrl[8 + r], 1u) == target - 1u)
      last = (atomicAdd(&ctrl[3], 1u) == 7u);
    s_last = last;
  }
  __syncthreads();
  if (!s_last) return;

  // ---- last block: ascending 256-bin select. Bin 0 = best scores. Find B
  //      with cum(0..B-1) < TOPK <= cum(0..B); superset = bins <= B (~4x1000).
  if (tid < 64) {
    uint32_t h[4];
    #pragma unroll
    for (int t = 0; t < 4; ++t) h[t] = atomLoadU32(&hist256[4 * tid + t]);
    uint32_t part = h[0] + h[1] + h[2] + h[3];
    uint32_t incl = part;
    #pragma unroll
    for (int d = 1; d < 64; d <<= 1) {
      uint32_t up = __shfl_up(incl, d);
      if (tid >= d) incl += up;
    }
    uint32_t excl = incl - part;
    if (excl < TOPK && TOPK <= incl) {     // exactly one lane
      uint32_t cum = excl;
      #pragma unroll
      for (int t = 0; t < 4; ++t) {
        if (cum + h[t] >= TOPK) {
          uint32_t B = 4u * tid + t;
          atomStoreU32(&ctrl[0], (B + 1u) << 24);  // excl. bound on bits(1-s)
          break;
        }
        cum += h[t];
      }
    }
  }
}

// ---- Phase 2: compact candidate superset (bits(1-s) < thrc) ----
__global__ __launch_bounds__(256) void k_compact(uint8_t* __restrict__ ws) {
  uint32_t* ctrl = (uint32_t*)(ws + OFF_CTRL);
  const uint64_t* keys = (const uint64_t*)(ws + OFF_KEYS);
  uint64_t* cand = (uint64_t*)(ws + OFF_CAND);
  const uint32_t thrc = ctrl[0];
  const int tid = threadIdx.x;
  for (int i = blockIdx.x * 256 + tid; i < N_PRIORS; i += 256 * HGRID) {
    uint64_t kk = keys[i];
    float s = __uint_as_float((uint32_t)(kk >> 32));
    if (cbits(s) < thrc) {                 // same transform as k_reduce: exact
      uint32_t pos = atomicAdd(&ctrl[2], 1u);
      if (pos < CAND_CAP) cand[pos] = kk;
    }
  }
}

// ---- Phase 3: exact rank (pairwise) + scatter top-1000 in top_k order ----
__global__ __launch_bounds__(256) void k_rank(const float* __restrict__ boxes,
                                              uint8_t* __restrict__ ws) {
  uint32_t* ctrl = (uint32_t*)(ws + OFF_CTRL);
  const uint64_t* cand = (const uint64_t*)(ws + OFF_CAND);
  const int32_t* labs = (const int32_t*)(ws + OFF_LABELS);
  float*   cscore = (float*)(ws + OFF_CSCORE);
  int32_t* clabel = (int32_t*)(ws + OFF_CLABEL);
  float*   craw   = (float*)(ws + OFF_CRAW);
  float*   obox   = (float*)(ws + OFF_OBOX);
  float*   oarea  = (float*)(ws + OFF_OAREA);
  uint64_t* validm = (uint64_t*)(ws + OFF_VALID);
  uint32_t c2 = ctrl[2];
  const uint32_t n = (c2 < CAND_CAP) ? c2 : CAND_CAP;
  const uint32_t j = blockIdx.x;
  if (j >= n) return;
  const uint64_t kj = cand[j];
  const int tid = threadIdx.x;
  uint32_t cnt = 0;
  for (uint32_t i = tid; i < n; i += 256) cnt += (cand[i] > kj) ? 1u : 0u;
  __shared__ uint32_t red[256];
  red[tid] = cnt;
  __syncthreads();
  #pragma unroll
  for (int s = 128; s > 0; s >>= 1) {
    if (tid < s) red[tid] += red[tid + s];
    __syncthreads();
  }
  if (tid == 0) {
    uint32_t rank = red[0];   // keys unique -> ranks unique & complete for top-1000
    if (rank < TOPK) {
      uint32_t idx = ~(uint32_t)kj;
      float sc = __uint_as_float((uint32_t)(kj >> 32));
      int lab = labs[idx];
      float bx0 = boxes[idx * 4 + 0];
      float bx1 = boxes[idx * 4 + 1];
      float bx2 = boxes[idx * 4 + 2];
      float bx3 = boxes[idx * 4 + 3];
      float off = (float)lab * 4.0f;
      float o0 = bx0 + off, o1 = bx1 + off, o2 = bx2 + off, o3 = bx3 + off;
      cscore[rank] = sc;
      clabel[rank] = lab;
      craw[rank * 4 + 0] = bx0; craw[rank * 4 + 1] = bx1;
      craw[rank * 4 + 2] = bx2; craw[rank * 4 + 3] = bx3;
      obox[rank * 4 + 0] = o0;  obox[rank * 4 + 1] = o1;
      obox[rank * 4 + 2] = o2;  obox[rank * 4 + 3] = o3;
      oarea[rank] = (o2 - o0) * (o3 - o1);
      if (sc > 0.3f)
        atomicOr((unsigned long long*)&validm[rank >> 6], 1ull << (rank & 63));
    }
  }
}

// ---- Phase 4: IoU rows (compacted) + (last block) LDS-cached serial NMS + output ----
__global__ __launch_bounds__(256) void k_iou_nms(float* __restrict__ out,
                                                 uint8_t* __restrict__ ws) {
  __shared__ uint64_t s_words[16];
  __shared__ uint32_t s_slotsh;
  __shared__ int s_last;
  __shared__ uint64_t s_keep[16];
  __shared__ uint16_t s_slot[TOPK];          // 2000 B
  __shared__ uint64_t s_cm[CM_CAP * 16];     // 57344 B

  uint32_t* ctrl = (uint32_t*)(ws + OFF_CTRL);
  const float* obox  = (const float*)(ws + OFF_OBOX);
  const float* oarea = (const float*)(ws + OFF_OAREA);
  uint64_t* CM  = (uint64_t*)(ws + OFF_CM);
  uint64_t* rnz = (uint64_t*)(ws + OFF_RNZ);
  uint32_t* slotmap = (uint32_t*)(ws + OFF_SLOT);
  const uint64_t* validm = (const uint64_t*)(ws + OFF_VALID);
  const float*   cscore = (const float*)(ws + OFF_CSCORE);
  const int32_t* clabel = (const int32_t*)(ws + OFF_CLABEL);
  const float*   craw   = (const float*)(ws + OFF_CRAW);

  const int i = blockIdx.x;
  const int tid = threadIdx.x;
  const float bi0 = obox[i * 4 + 0], bi1 = obox[i * 4 + 1];
  const float bi2 = obox[i * 4 + 2], bi3 = obox[i * 4 + 3];
  const float ai = oarea[i];
  #pragma unroll
  for (int k = 0; k < 4; ++k) {
    int j = tid + 256 * k;                      // [0,1024); tail zeroed
    const float4 bj = ((const float4*)obox)[j];
    float x1 = fmaxf(bi0, bj.x);
    float y1 = fmaxf(bi1, bj.y);
    float x2 = fminf(bi2, bj.z);
    float y2 = fminf(bi3, bj.w);
    float iw = fmaxf(x2 - x1, 0.0f);
    float ih = fmaxf(y2 - y1, 0.0f);
    float inter = iw * ih;
    float uni = ai + oarea[j] - inter;
    float iou = inter / fmaxf(uni, 1e-9f);
    bool pred = (iou > 0.5f) && (j > i) && (j < TOPK);
    uint64_t m = __ballot(pred);
    if ((tid & 63) == 0) s_words[(tid >> 6) + 4 * k] = m;
  }
  __syncthreads();
  if (tid == 0) {
    uint64_t any = 0;
    #pragma unroll
    for (int w = 0; w < 16; ++w) any |= s_words[w];
    uint32_t sl = 0xFFFFFFFFu;
    if (any) {
      sl = atomicAdd(&ctrl[7], 1u);
      atomicOr((unsigned long long*)&rnz[i >> 6], 1ull << (i & 63));
      atomStoreU32(&slotmap[i], sl + 1u);
    }
    s_slotsh = sl;
  }
  __syncthreads();
  {
    uint32_t sl = s_slotsh;
    if (sl != 0xFFFFFFFFu && tid < 16)
      atomStoreU64(&CM[(size_t)sl * 16 + tid], s_words[tid]);
  }
  __syncthreads();                            // drain before done-count
  if (tid == 0) s_last = (atomicAdd(&ctrl[6], 1u) == (uint32_t)(TOPK - 1));
  __syncthreads();
  if (!s_last) return;

  // ---- last block: prefetch compacted rows to LDS, serial NMS, outputs ----
  uint32_t cmcnt = atomLoadU32(&ctrl[7]);     // <= 1000
  uint32_t ncm = cmcnt < CM_CAP ? cmcnt : CM_CAP;
  for (int r = tid; r < TOPK; r += 256)
    s_slot[r] = (uint16_t)atomLoadU32(&slotmap[r]);
  for (uint32_t x = tid; x < ncm * 16; x += 256)
    s_cm[x] = atomLoadU64(&CM[x]);
  __syncthreads();

  if (tid < 64) {
    const int lane = tid;
    uint64_t keep = 0, rz = 0;
    if (lane < 16) {
      keep = validm[lane];            // written by previous kernel (boundary-coherent)
      rz = atomLoadU64(&rnz[lane]);
    }
    for (int w = 0; w < 16; ++w) {
      uint64_t rw = __shfl(rz, w);
      int start = 0;
      while (true) {
        uint64_t kw = __shfl(keep, w);
        uint64_t act = kw & rw;
        if (start) act &= (~0ull) << start;
        if (!act) break;
        int il = __builtin_ctzll(act);
        int row = w * 64 + il;
        uint32_t sv = s_slot[row];
        uint64_t m = 0;
        if (lane < 16 && sv) {
          uint32_t s = sv - 1u;
          m = (s < ncm) ? s_cm[s * 16 + lane]
                        : atomLoadU64(&CM[(size_t)s * 16 + lane]);
        }
        keep &= ~m;
        if (il >= 63) break;
        start = il + 1;
      }
    }
    if (lane < 16) s_keep[lane] = keep;
  }
  __syncthreads();

  // outputs: boxes[4000] | labels[1000] | probs[1000] | keep[1000], all f32
  for (int e = tid; e < 4000; e += 256) {
    int j = e >> 2;
    bool kp = (s_keep[j >> 6] >> (j & 63)) & 1ull;
    out[e] = kp ? craw[e] : 0.0f;
  }
  for (int j = tid; j < TOPK; j += 256) {
    bool kp = (s_keep[j >> 6] >> (j & 63)) & 1ull;
    out[4000 + j] = kp ? (float)(clabel[j] + 1) : 0.0f;
    out[5000 + j] = kp ? cscore[j] : 0.0f;
    out[6000 + j] = kp ? 1.0f : 0.0f;
  }
}

extern "C" void kernel_launch(void* const* d_in, const int* in_sizes, int n_in,
                              void* d_out, int out_size, void* d_ws, size_t ws_size,
                              hipStream_t stream) {
  const float* scores = (const float*)d_in[0];
  const float* boxes  = (const float*)d_in[1];
  float* out = (float*)d_out;
  uint8_t* ws = (uint8_t*)d_ws;

  (void)in_sizes; (void)n_in; (void)out_size; (void)ws_size;

  hipMemsetAsync(d_ws, 0, 65536, stream);   // ctrl + hist256 + small buffers
  k_reduce<<<RED_BLOCKS, 256, 0, stream>>>(scores, ws);
  k_compact<<<HGRID, 256, 0, stream>>>(ws);
  k_rank<<<CAND_CAP, 256, 0, stream>>>(boxes, ws);
  k_iou_nms<<<TOPK, 256, 0, stream>>>(out, ws);
}